// Round 3
// baseline (4729.580 us; speedup 1.0000x reference)
//
#include <hip/hip_runtime.h>
#include <cstdint>
#include <cstddef>
#include <cstdio>

// Problem constants (fixed by the reference)
namespace {
constexpr int EMB    = 1024;
constexpr int HID    = 2048;
constexpr int FOURH  = 4 * HID;       // 8192
constexpr int NHEADS = 16;
constexpr int HD     = HID / NHEADS;  // 128
constexpr int BSZ    = 4;
constexpr int SEQ    = 4096;
constexpr int M_TOT  = BSZ * SEQ;     // 16384
constexpr int CH     = 256;           // scan chunk length (timesteps)
constexpr int NC     = SEQ / CH;      // 16 chunks per sequence
constexpr int BH     = BSZ * NHEADS;  // 64 batch-heads
}

// ---------------------------------------------------------------------------
// GEMM: C[M,N] = A[M,K] * B[N,K]^T  (row-major, K-major dot). LDA/LDC allow
// strided views (gate lives inside y with lda=8192).
// 128x128 tile, BK=16, 256 threads, 8x8 micro-tile per thread.
// ---------------------------------------------------------------------------
template<int K, int LDA, int LDC>
__global__ __launch_bounds__(256, 2)
void gemm_nt(const float* __restrict__ A, const float* __restrict__ Bm,
             float* __restrict__ C)
{
    constexpr int BMt = 128, BKt = 16;
    constexpr int PITCH = BMt + 4;
    __shared__ float As[BKt][PITCH];
    __shared__ float Bs[BKt][PITCH];

    const int tid = threadIdx.x;
    const int m0 = blockIdx.y * BMt;
    const int n0 = blockIdx.x * BMt;

    const int lrow = tid >> 2;        // 0..63
    const int lk   = (tid & 3) * 4;   // 0,4,8,12

    const float* Ap = A  + (size_t)(m0 + lrow) * LDA + lk;
    const float* Bp = Bm + (size_t)(n0 + lrow) * K + lk;

    const int tx = tid & 15;   // n-direction
    const int ty = tid >> 4;   // m-direction

    float4 ar0, ar1, br0, br1;

    float acc[8][8];
#pragma unroll
    for (int i = 0; i < 8; ++i)
#pragma unroll
        for (int j = 0; j < 8; ++j) acc[i][j] = 0.f;

    constexpr int NKT = K / BKt;

    // prefetch tile 0
    ar0 = *(const float4*)(Ap);
    ar1 = *(const float4*)(Ap + (size_t)64 * LDA);
    br0 = *(const float4*)(Bp);
    br1 = *(const float4*)(Bp + (size_t)64 * K);

    for (int kt = 0; kt < NKT; ++kt) {
        As[lk+0][lrow]    = ar0.x; As[lk+1][lrow]    = ar0.y;
        As[lk+2][lrow]    = ar0.z; As[lk+3][lrow]    = ar0.w;
        As[lk+0][lrow+64] = ar1.x; As[lk+1][lrow+64] = ar1.y;
        As[lk+2][lrow+64] = ar1.z; As[lk+3][lrow+64] = ar1.w;
        Bs[lk+0][lrow]    = br0.x; Bs[lk+1][lrow]    = br0.y;
        Bs[lk+2][lrow]    = br0.z; Bs[lk+3][lrow]    = br0.w;
        Bs[lk+0][lrow+64] = br1.x; Bs[lk+1][lrow+64] = br1.y;
        Bs[lk+2][lrow+64] = br1.z; Bs[lk+3][lrow+64] = br1.w;
        __syncthreads();

        if (kt + 1 < NKT) {
            const float* a = Ap + (kt + 1) * BKt;
            const float* b = Bp + (kt + 1) * BKt;
            ar0 = *(const float4*)(a);
            ar1 = *(const float4*)(a + (size_t)64 * LDA);
            br0 = *(const float4*)(b);
            br1 = *(const float4*)(b + (size_t)64 * K);
        }

#pragma unroll
        for (int k = 0; k < BKt; ++k) {
            float4 a0 = *(const float4*)&As[k][ty * 4];
            float4 a1 = *(const float4*)&As[k][64 + ty * 4];
            float4 b0 = *(const float4*)&Bs[k][tx * 4];
            float4 b1 = *(const float4*)&Bs[k][64 + tx * 4];
            float av[8] = {a0.x, a0.y, a0.z, a0.w, a1.x, a1.y, a1.z, a1.w};
            float bv[8] = {b0.x, b0.y, b0.z, b0.w, b1.x, b1.y, b1.z, b1.w};
#pragma unroll
            for (int i = 0; i < 8; ++i)
#pragma unroll
                for (int j = 0; j < 8; ++j)
                    acc[i][j] += av[i] * bv[j];
        }
        __syncthreads();
    }

#pragma unroll
    for (int i = 0; i < 8; ++i) {
        const int mi = m0 + ((i < 4) ? (ty * 4 + i) : (64 + ty * 4 + (i - 4)));
        float* crow = C + (size_t)mi * LDC + n0;
        *(float4*)(crow + tx * 4)      = make_float4(acc[i][0], acc[i][1], acc[i][2], acc[i][3]);
        *(float4*)(crow + 64 + tx * 4) = make_float4(acc[i][4], acc[i][5], acc[i][6], acc[i][7]);
    }
}

// ---------------------------------------------------------------------------
// Scan: conv(K=4, causal) -> sigmoid -> a,b -> h_t = a*h_{t-1} + b
// 3-pass chunked scan. Block = 128 threads = 128 channels of one head.
// Kernels operate on a y view of NB batches (NB=4 full path, NB=1 sliced);
// bh = blockIdx.y in [0, NB*16), b = bh>>4 indexes within the view.
// ---------------------------------------------------------------------------
__device__ __forceinline__ float sigmoidf_(float x) {
    return 1.f / (1.f + __expf(-x));
}

__global__ __launch_bounds__(128)
void scan_pass1(const float* __restrict__ y, const float* __restrict__ cw,
                float* __restrict__ chunkA, float* __restrict__ chunkB)
{
    const int d     = threadIdx.x;
    const int chunk = blockIdx.x;
    const int bh    = blockIdx.y;
    const int b = bh >> 4, n = bh & 15;
    const int s0 = chunk * CH;

    const int cf  = 2 * HID + n * (2 * HD) + d;
    const int ci  = cf + HD;
    const int chh = HID + n * HD + d;

    const float* yb = y + (size_t)b * SEQ * FOURH;

    const float4 wf = *(const float4*)(cw + (size_t)(n * (2 * HD) + d) * 4);
    const float4 wi = *(const float4*)(cw + (size_t)(n * (2 * HD) + HD + d) * 4);

    float f1 = 0.f, f2 = 0.f, f3 = 0.f, i1 = 0.f, i2 = 0.f, i3 = 0.f;
    if (s0 > 0) {
        f1 = yb[(size_t)(s0 - 3) * FOURH + cf];
        f2 = yb[(size_t)(s0 - 2) * FOURH + cf];
        f3 = yb[(size_t)(s0 - 1) * FOURH + cf];
        i1 = yb[(size_t)(s0 - 3) * FOURH + ci];
        i2 = yb[(size_t)(s0 - 2) * FOURH + ci];
        i3 = yb[(size_t)(s0 - 1) * FOURH + ci];
    }

    float A = 1.f, Bv = 0.f;
    const float* row = yb + (size_t)s0 * FOURH;
#pragma unroll 4
    for (int s = 0; s < CH; ++s, row += FOURH) {
        const float f0 = row[cf];
        const float i0 = row[ci];
        const float hh = row[chh];
        const float fc = wf.x * f1 + wf.y * f2 + wf.z * f3 + wf.w * f0;
        const float ic = wi.x * i1 + wi.y * i2 + wi.z * i3 + wi.w * i0;
        f1 = f2; f2 = f3; f3 = f0;
        i1 = i2; i2 = i3; i3 = i0;
        const float fs = sigmoidf_(fc);
        const float is = sigmoidf_(ic);
        const float dn = 1.f / (fs + is + 1e-4f);
        const float a  = fs * dn;
        const float bb = hh * is * dn;
        Bv = a * Bv + bb;
        A *= a;
    }
    const size_t idx = ((size_t)bh * NC + chunk) * HD + d;
    chunkA[idx] = A;
    chunkB[idx] = Bv;
}

__global__ __launch_bounds__(128)
void scan_pass2(const float* __restrict__ chunkA, const float* __restrict__ chunkB,
                float* __restrict__ hin)
{
    const int d  = threadIdx.x;
    const int bh = blockIdx.x;
    float h = 0.f;
    for (int c = 0; c < NC; ++c) {
        const size_t idx = ((size_t)bh * NC + c) * HD + d;
        hin[idx] = h;
        h = chunkA[idx] * h + chunkB[idx];
    }
}

// Pass 3: re-scan with true incoming state; write silu(out1)*h IN PLACE into
// the out1 column block of y (columns [0, HID)). Race-free: each (row, col)
// is touched by exactly one thread, and nothing else reads out1 afterwards.
__global__ __launch_bounds__(128)
void scan_pass3(float* __restrict__ y, const float* __restrict__ cw,
                const float* __restrict__ hin)
{
    const int d     = threadIdx.x;
    const int chunk = blockIdx.x;
    const int bh    = blockIdx.y;
    const int b = bh >> 4, n = bh & 15;
    const int s0 = chunk * CH;

    const int cf  = 2 * HID + n * (2 * HD) + d;
    const int ci  = cf + HD;
    const int chh = HID + n * HD + d;
    const int co1 = n * HD + d;

    float* yb = y + (size_t)b * SEQ * FOURH;

    const float4 wf = *(const float4*)(cw + (size_t)(n * (2 * HD) + d) * 4);
    const float4 wi = *(const float4*)(cw + (size_t)(n * (2 * HD) + HD + d) * 4);

    float f1 = 0.f, f2 = 0.f, f3 = 0.f, i1 = 0.f, i2 = 0.f, i3 = 0.f;
    if (s0 > 0) {
        f1 = yb[(size_t)(s0 - 3) * FOURH + cf];
        f2 = yb[(size_t)(s0 - 2) * FOURH + cf];
        f3 = yb[(size_t)(s0 - 1) * FOURH + cf];
        i1 = yb[(size_t)(s0 - 3) * FOURH + ci];
        i2 = yb[(size_t)(s0 - 2) * FOURH + ci];
        i3 = yb[(size_t)(s0 - 1) * FOURH + ci];
    }

    float h = hin[((size_t)bh * NC + chunk) * HD + d];

    float* row = yb + (size_t)s0 * FOURH;
#pragma unroll 4
    for (int s = 0; s < CH; ++s, row += FOURH) {
        const float f0 = row[cf];
        const float i0 = row[ci];
        const float hh = row[chh];
        const float fc = wf.x * f1 + wf.y * f2 + wf.z * f3 + wf.w * f0;
        const float ic = wi.x * i1 + wi.y * i2 + wi.z * i3 + wi.w * i0;
        f1 = f2; f2 = f3; f3 = f0;
        i1 = i2; i2 = i3; i3 = i0;
        const float fs = sigmoidf_(fc);
        const float is = sigmoidf_(ic);
        const float dn = 1.f / (fs + is + 1e-4f);
        const float a  = fs * dn;
        const float bb = hh * is * dn;
        h = a * h + bb;
        const float o1  = row[co1];
        const float sil = o1 * sigmoidf_(o1);
        row[co1] = sil * h;   // gate, in place
    }
}

// ---------------------------------------------------------------------------
extern "C" void kernel_launch(void* const* d_in, const int* in_sizes, int n_in,
                              void* d_out, int out_size, void* d_ws, size_t ws_size,
                              hipStream_t stream)
{
    (void)in_sizes; (void)n_in;
    const float* x  = (const float*)d_in[0];   // [B,S,E]
    const float* w1 = (const float*)d_in[1];   // [4H,E]
    const float* w2 = (const float*)d_in[2];   // [E,H]
    const float* cw = (const float*)d_in[3];   // [2H,4]
    float* out = (float*)d_out;                // [B,S,E]

    const size_t sideFloats = (size_t)3 * BH * NC * HD;                 // 1.5 MB worth
    const size_t fullBytes  = (size_t)M_TOT * FOURH * sizeof(float)
                            + sideFloats * sizeof(float);               // ~513.5 MB
    const size_t sliceBytes = (size_t)SEQ * FOURH * sizeof(float)
                            + sideFloats * sizeof(float);               // ~129.5 MB

    char* ws = (char*)d_ws;

    if (ws_size >= fullBytes) {
        // ---- full-M path (fastest) ----
        float* y      = (float*)ws;                                     // [16384, 8192]
        float* chunkA = (float*)(ws + (size_t)M_TOT * FOURH * sizeof(float));
        float* chunkB = chunkA + (size_t)BH * NC * HD;
        float* hin    = chunkB + (size_t)BH * NC * HD;

        dim3 g1(FOURH / 128, M_TOT / 128);
        gemm_nt<EMB, EMB, FOURH><<<g1, 256, 0, stream>>>(x, w1, y);

        dim3 gs(NC, BH);
        scan_pass1<<<gs, 128, 0, stream>>>(y, cw, chunkA, chunkB);
        scan_pass2<<<BH, 128, 0, stream>>>(chunkA, chunkB, hin);
        scan_pass3<<<gs, 128, 0, stream>>>(y, cw, hin);

        dim3 g2(EMB / 128, M_TOT / 128);
        gemm_nt<HID, FOURH, EMB><<<g2, 256, 0, stream>>>(y, w2, out);
    } else if (ws_size >= sliceBytes) {
        // ---- per-batch sliced path (needs ~129.5 MB) ----
        float* y      = (float*)ws;                                     // [4096, 8192]
        float* chunkA = (float*)(ws + (size_t)SEQ * FOURH * sizeof(float));
        float* chunkB = chunkA + (size_t)NHEADS * NC * HD;
        float* hin    = chunkB + (size_t)NHEADS * NC * HD;

        for (int b = 0; b < BSZ; ++b) {
            const float* xb = x   + (size_t)b * SEQ * EMB;
            float*       ob = out + (size_t)b * SEQ * EMB;

            dim3 g1(FOURH / 128, SEQ / 128);
            gemm_nt<EMB, EMB, FOURH><<<g1, 256, 0, stream>>>(xb, w1, y);

            dim3 gs(NC, NHEADS);   // bh in [0,16): b-within-view = 0
            scan_pass1<<<gs, 128, 0, stream>>>(y, cw, chunkA, chunkB);
            scan_pass2<<<NHEADS, 128, 0, stream>>>(chunkA, chunkB, hin);
            scan_pass3<<<gs, 128, 0, stream>>>(y, cw, hin);

            dim3 g2(EMB / 128, SEQ / 128);
            gemm_nt<HID, FOURH, EMB><<<g2, 256, 0, stream>>>(y, w2, ob);
        }
    } else {
        // Diagnostic fallback: report budget instead of faulting.
        fprintf(stderr, "[kernel_launch] ws_size=%zu < sliceBytes=%zu — aborting cleanly\n",
                ws_size, sliceBytes);
        hipMemsetAsync(d_out, 0, (size_t)out_size * sizeof(float), stream);
    }
}

// Round 4
// 3533.878 us; speedup vs baseline: 1.3384x; 1.3384x over previous
//
#include <hip/hip_runtime.h>
#include <cstdint>
#include <cstddef>
#include <cstdio>

// Problem constants (fixed by the reference)
namespace {
constexpr int EMB    = 1024;
constexpr int HID    = 2048;
constexpr int FOURH  = 4 * HID;       // 8192
constexpr int NHEADS = 16;
constexpr int HD     = HID / NHEADS;  // 128
constexpr int BSZ    = 4;
constexpr int SEQ    = 4096;
constexpr int M_TOT  = BSZ * SEQ;     // 16384
constexpr int CH     = 256;           // scan chunk length
constexpr int NC     = SEQ / CH;      // 16
constexpr int BH     = BSZ * NHEADS;  // 64

constexpr int BM = 128, BN = 128, BK = 32;
constexpr int LDT = 40;               // LDS row pitch in ushorts (pad: 2-way banks only)
}

typedef short  bf16x8  __attribute__((ext_vector_type(8)));
typedef float  f32x4   __attribute__((ext_vector_type(4)));
typedef unsigned short usx4 __attribute__((ext_vector_type(4)));
typedef unsigned short usx8 __attribute__((ext_vector_type(8)));

__device__ __forceinline__ unsigned short f2bf(float x) {
    uint32_t u = __float_as_uint(x);
    u += 0x7FFFu + ((u >> 16) & 1u);          // RNE
    return (unsigned short)(u >> 16);
}
__device__ __forceinline__ float bf2f(unsigned short h) {
    return __uint_as_float(((uint32_t)h) << 16);
}
__device__ __forceinline__ void split_store4(const float4 v,
                                             unsigned short* __restrict__ dh,
                                             unsigned short* __restrict__ dl) {
    usx4 h, l;
    h[0] = f2bf(v.x); l[0] = f2bf(v.x - bf2f(h[0]));
    h[1] = f2bf(v.y); l[1] = f2bf(v.y - bf2f(h[1]));
    h[2] = f2bf(v.z); l[2] = f2bf(v.z - bf2f(h[2]));
    h[3] = f2bf(v.w); l[3] = f2bf(v.w - bf2f(h[3]));
    *(usx4*)dh = h;
    *(usx4*)dl = l;
}

// ---------------------------------------------------------------------------
// Split-bf16 MFMA GEMM: C[M,N] = A[M,K] * B[N,K]^T
//   a*b ~= ah*bh + ah*bl + al*bh  (al*bl dropped, ~2^-16 rel)
// B is always fp32 (weights), split on the fly.
// ASPLIT: A comes pre-split as two bf16 planes (Ah/Al, lda in ushorts).
// CSPLIT: C written as two bf16 planes (Ch/Cl), else fp32 Cf.
// 256 threads = 4 waves; wave computes 64x64 via 4x4 frags of 16x16x32.
// ---------------------------------------------------------------------------
template<int K, bool ASPLIT, bool CSPLIT, int LDA, int LDC>
__global__ __launch_bounds__(256, 2)
void gemm_mfma(const float* __restrict__ Af,
               const unsigned short* __restrict__ Ah,
               const unsigned short* __restrict__ Al,
               const float* __restrict__ Bf,
               float* __restrict__ Cf,
               unsigned short* __restrict__ Ch,
               unsigned short* __restrict__ Cl)
{
    __shared__ unsigned short Ash[BM][LDT], Asl[BM][LDT];
    __shared__ unsigned short Bsh[BN][LDT], Bsl[BN][LDT];

    const int tid  = threadIdx.x;
    const int lane = tid & 63;
    const int wv   = tid >> 6;
    const int wr   = (wv >> 1) * 64;   // wave m-offset in tile
    const int wc   = (wv & 1) * 64;    // wave n-offset in tile
    const int m0   = blockIdx.y * BM;
    const int n0   = blockIdx.x * BN;

    const int srow = tid >> 1;         // staging row 0..127
    const int skq  = (tid & 1) * 16;   // staging k-offset 0/16

    f32x4 acc[4][4];
#pragma unroll
    for (int i = 0; i < 4; ++i)
#pragma unroll
        for (int j = 0; j < 4; ++j) acc[i][j] = (f32x4){0.f, 0.f, 0.f, 0.f};

    constexpr int NKT = K / BK;

    // staging registers
    float4 b0, b1, b2, b3;
    float4 a0, a1, a2, a3;     // !ASPLIT path
    usx8 ah0, ah1, al0, al1;   // ASPLIT path

    auto prefetch = [&](int kt) {
        const float* bp = Bf + (size_t)(n0 + srow) * K + kt * BK + skq;
        b0 = *(const float4*)(bp + 0);
        b1 = *(const float4*)(bp + 4);
        b2 = *(const float4*)(bp + 8);
        b3 = *(const float4*)(bp + 12);
        if constexpr (!ASPLIT) {
            const float* ap = Af + (size_t)(m0 + srow) * LDA + kt * BK + skq;
            a0 = *(const float4*)(ap + 0);
            a1 = *(const float4*)(ap + 4);
            a2 = *(const float4*)(ap + 8);
            a3 = *(const float4*)(ap + 12);
        } else {
            const unsigned short* ph = Ah + (size_t)(m0 + srow) * LDA + kt * BK + skq;
            const unsigned short* pl = Al + (size_t)(m0 + srow) * LDA + kt * BK + skq;
            ah0 = *(const usx8*)(ph);
            ah1 = *(const usx8*)(ph + 8);
            al0 = *(const usx8*)(pl);
            al1 = *(const usx8*)(pl + 8);
        }
    };

    prefetch(0);

    for (int kt = 0; kt < NKT; ++kt) {
        __syncthreads();   // prior iteration's frag reads done before overwrite
        // stage regs -> LDS (with fp32 -> hi/lo split where needed)
        split_store4(b0, &Bsh[srow][skq + 0],  &Bsl[srow][skq + 0]);
        split_store4(b1, &Bsh[srow][skq + 4],  &Bsl[srow][skq + 4]);
        split_store4(b2, &Bsh[srow][skq + 8],  &Bsl[srow][skq + 8]);
        split_store4(b3, &Bsh[srow][skq + 12], &Bsl[srow][skq + 12]);
        if constexpr (!ASPLIT) {
            split_store4(a0, &Ash[srow][skq + 0],  &Asl[srow][skq + 0]);
            split_store4(a1, &Ash[srow][skq + 4],  &Asl[srow][skq + 4]);
            split_store4(a2, &Ash[srow][skq + 8],  &Asl[srow][skq + 8]);
            split_store4(a3, &Ash[srow][skq + 12], &Asl[srow][skq + 12]);
        } else {
            *(usx8*)&Ash[srow][skq + 0] = ah0;
            *(usx8*)&Ash[srow][skq + 8] = ah1;
            *(usx8*)&Asl[srow][skq + 0] = al0;
            *(usx8*)&Asl[srow][skq + 8] = al1;
        }
        __syncthreads();

        if (kt + 1 < NKT) prefetch(kt + 1);   // overlap HBM with MFMA below

        const int fr = lane & 15;
        const int fk = (lane >> 4) * 8;
        bf16x8 fah[4], fal[4], fbh[4], fbl[4];
#pragma unroll
        for (int i = 0; i < 4; ++i) {
            fah[i] = *(const bf16x8*)&Ash[wr + i * 16 + fr][fk];
            fal[i] = *(const bf16x8*)&Asl[wr + i * 16 + fr][fk];
            fbh[i] = *(const bf16x8*)&Bsh[wc + i * 16 + fr][fk];
            fbl[i] = *(const bf16x8*)&Bsl[wc + i * 16 + fr][fk];
        }
#pragma unroll
        for (int i = 0; i < 4; ++i)
#pragma unroll
            for (int j = 0; j < 4; ++j) {
                acc[i][j] = __builtin_amdgcn_mfma_f32_16x16x32_bf16(fah[i], fbh[j], acc[i][j], 0, 0, 0);
                acc[i][j] = __builtin_amdgcn_mfma_f32_16x16x32_bf16(fah[i], fbl[j], acc[i][j], 0, 0, 0);
                acc[i][j] = __builtin_amdgcn_mfma_f32_16x16x32_bf16(fal[i], fbh[j], acc[i][j], 0, 0, 0);
            }
    }

    // epilogue: C/D frag layout col = lane&15, row = (lane>>4)*4 + r  [m89/m91]
    const int fr = lane & 15;
    const int fq = lane >> 4;
#pragma unroll
    for (int i = 0; i < 4; ++i)
#pragma unroll
        for (int j = 0; j < 4; ++j)
#pragma unroll
            for (int r = 0; r < 4; ++r) {
                const int row = m0 + wr + i * 16 + fq * 4 + r;
                const int col = n0 + wc + j * 16 + fr;
                const float v = acc[i][j][r];
                if constexpr (CSPLIT) {
                    const unsigned short h = f2bf(v);
                    Ch[(size_t)row * LDC + col] = h;
                    Cl[(size_t)row * LDC + col] = f2bf(v - bf2f(h));
                } else {
                    Cf[(size_t)row * LDC + col] = v;
                }
            }
}

// ---------------------------------------------------------------------------
// Scan over split-bf16 y: conv(K=4) -> sigmoid -> recurrence. 3-pass chunked.
// Block = 128 threads = 128 channels of one head. b = bh>>4 within the y view.
// ---------------------------------------------------------------------------
__device__ __forceinline__ float sigmoidf_(float x) {
    return 1.f / (1.f + __expf(-x));
}
__device__ __forceinline__ float yld(const unsigned short* __restrict__ yh,
                                     const unsigned short* __restrict__ yl,
                                     size_t idx) {
    return bf2f(yh[idx]) + bf2f(yl[idx]);
}

__global__ __launch_bounds__(128)
void scan_pass1(const unsigned short* __restrict__ yh,
                const unsigned short* __restrict__ yl,
                const float* __restrict__ cw,
                float* __restrict__ chunkA, float* __restrict__ chunkB)
{
    const int d     = threadIdx.x;
    const int chunk = blockIdx.x;
    const int bh    = blockIdx.y;
    const int b = bh >> 4, n = bh & 15;
    const int s0 = chunk * CH;

    const int cf  = 2 * HID + n * (2 * HD) + d;
    const int ci  = cf + HD;
    const int chh = HID + n * HD + d;

    const size_t base = (size_t)b * SEQ * FOURH;
    const float4 wf = *(const float4*)(cw + (size_t)(n * (2 * HD) + d) * 4);
    const float4 wi = *(const float4*)(cw + (size_t)(n * (2 * HD) + HD + d) * 4);

    float f1 = 0.f, f2 = 0.f, f3 = 0.f, i1 = 0.f, i2 = 0.f, i3 = 0.f;
    if (s0 > 0) {
        f1 = yld(yh, yl, base + (size_t)(s0 - 3) * FOURH + cf);
        f2 = yld(yh, yl, base + (size_t)(s0 - 2) * FOURH + cf);
        f3 = yld(yh, yl, base + (size_t)(s0 - 1) * FOURH + cf);
        i1 = yld(yh, yl, base + (size_t)(s0 - 3) * FOURH + ci);
        i2 = yld(yh, yl, base + (size_t)(s0 - 2) * FOURH + ci);
        i3 = yld(yh, yl, base + (size_t)(s0 - 1) * FOURH + ci);
    }

    float A = 1.f, Bv = 0.f;
    size_t rowb = base + (size_t)s0 * FOURH;
#pragma unroll 4
    for (int s = 0; s < CH; ++s, rowb += FOURH) {
        const float f0 = yld(yh, yl, rowb + cf);
        const float i0 = yld(yh, yl, rowb + ci);
        const float hh = yld(yh, yl, rowb + chh);
        const float fc = wf.x * f1 + wf.y * f2 + wf.z * f3 + wf.w * f0;
        const float ic = wi.x * i1 + wi.y * i2 + wi.z * i3 + wi.w * i0;
        f1 = f2; f2 = f3; f3 = f0;
        i1 = i2; i2 = i3; i3 = i0;
        const float fs = sigmoidf_(fc);
        const float is = sigmoidf_(ic);
        const float dn = 1.f / (fs + is + 1e-4f);
        const float a  = fs * dn;
        const float bb = hh * is * dn;
        Bv = a * Bv + bb;
        A *= a;
    }
    const size_t idx = ((size_t)bh * NC + chunk) * HD + d;
    chunkA[idx] = A;
    chunkB[idx] = Bv;
}

__global__ __launch_bounds__(128)
void scan_pass2(const float* __restrict__ chunkA, const float* __restrict__ chunkB,
                float* __restrict__ hin)
{
    const int d  = threadIdx.x;
    const int bh = blockIdx.x;
    float h = 0.f;
    for (int c = 0; c < NC; ++c) {
        const size_t idx = ((size_t)bh * NC + c) * HD + d;
        hin[idx] = h;
        h = chunkA[idx] * h + chunkB[idx];
    }
}

// Pass 3: re-scan with true incoming state; write silu(out1)*h as hi/lo IN
// PLACE into the out1 columns of yh/yl. Race-free (1 thread per element).
__global__ __launch_bounds__(128)
void scan_pass3(unsigned short* __restrict__ yh,
                unsigned short* __restrict__ yl,
                const float* __restrict__ cw,
                const float* __restrict__ hin)
{
    const int d     = threadIdx.x;
    const int chunk = blockIdx.x;
    const int bh    = blockIdx.y;
    const int b = bh >> 4, n = bh & 15;
    const int s0 = chunk * CH;

    const int cf  = 2 * HID + n * (2 * HD) + d;
    const int ci  = cf + HD;
    const int chh = HID + n * HD + d;
    const int co1 = n * HD + d;

    const size_t base = (size_t)b * SEQ * FOURH;
    const float4 wf = *(const float4*)(cw + (size_t)(n * (2 * HD) + d) * 4);
    const float4 wi = *(const float4*)(cw + (size_t)(n * (2 * HD) + HD + d) * 4);

    float f1 = 0.f, f2 = 0.f, f3 = 0.f, i1 = 0.f, i2 = 0.f, i3 = 0.f;
    if (s0 > 0) {
        f1 = yld(yh, yl, base + (size_t)(s0 - 3) * FOURH + cf);
        f2 = yld(yh, yl, base + (size_t)(s0 - 2) * FOURH + cf);
        f3 = yld(yh, yl, base + (size_t)(s0 - 1) * FOURH + cf);
        i1 = yld(yh, yl, base + (size_t)(s0 - 3) * FOURH + ci);
        i2 = yld(yh, yl, base + (size_t)(s0 - 2) * FOURH + ci);
        i3 = yld(yh, yl, base + (size_t)(s0 - 1) * FOURH + ci);
    }

    float h = hin[((size_t)bh * NC + chunk) * HD + d];

    size_t rowb = base + (size_t)s0 * FOURH;
#pragma unroll 4
    for (int s = 0; s < CH; ++s, rowb += FOURH) {
        const float f0 = yld(yh, yl, rowb + cf);
        const float i0 = yld(yh, yl, rowb + ci);
        const float hv = yld(yh, yl, rowb + chh);
        const float fc = wf.x * f1 + wf.y * f2 + wf.z * f3 + wf.w * f0;
        const float ic = wi.x * i1 + wi.y * i2 + wi.z * i3 + wi.w * i0;
        f1 = f2; f2 = f3; f3 = f0;
        i1 = i2; i2 = i3; i3 = i0;
        const float fs = sigmoidf_(fc);
        const float is = sigmoidf_(ic);
        const float dn = 1.f / (fs + is + 1e-4f);
        const float a  = fs * dn;
        const float bb = hv * is * dn;
        h = a * h + bb;
        const float o1  = yld(yh, yl, rowb + co1);
        const float g   = o1 * sigmoidf_(o1) * h;  // silu(out1) * h
        const unsigned short gh = f2bf(g);
        yh[rowb + co1] = gh;
        yl[rowb + co1] = f2bf(g - bf2f(gh));
    }
}

// ---------------------------------------------------------------------------
extern "C" void kernel_launch(void* const* d_in, const int* in_sizes, int n_in,
                              void* d_out, int out_size, void* d_ws, size_t ws_size,
                              hipStream_t stream)
{
    (void)in_sizes; (void)n_in;
    const float* x  = (const float*)d_in[0];   // [B,S,E]
    const float* w1 = (const float*)d_in[1];   // [4H,E]
    const float* w2 = (const float*)d_in[2];   // [E,H]
    const float* cw = (const float*)d_in[3];   // [2H,4]
    float* out = (float*)d_out;                // [B,S,E]

    const size_t sideFloats = (size_t)3 * BH * NC * HD;                    // 1.5 MB worth
    const size_t fullY   = (size_t)M_TOT * FOURH * sizeof(unsigned short); // 256 MiB per plane... (hi+lo = 512 MiB)
    const size_t sliceY  = (size_t)SEQ * FOURH * sizeof(unsigned short);   // 64 MiB per plane
    const size_t fullBytes  = 2 * fullY  + sideFloats * sizeof(float);
    const size_t sliceBytes = 2 * sliceY + sideFloats * sizeof(float);

    char* ws = (char*)d_ws;

    if (ws_size >= fullBytes) {
        // ---- full-M path ----
        unsigned short* yh = (unsigned short*)ws;
        unsigned short* yl = yh + (size_t)M_TOT * FOURH;
        float* chunkA = (float*)(ws + 2 * fullY);
        float* chunkB = chunkA + (size_t)BH * NC * HD;
        float* hin    = chunkB + (size_t)BH * NC * HD;

        dim3 g1(FOURH / BN, M_TOT / BM);
        gemm_mfma<EMB, false, true, EMB, FOURH><<<g1, 256, 0, stream>>>(
            x, nullptr, nullptr, w1, nullptr, yh, yl);

        dim3 gs(NC, BH);
        scan_pass1<<<gs, 128, 0, stream>>>(yh, yl, cw, chunkA, chunkB);
        scan_pass2<<<BH, 128, 0, stream>>>(chunkA, chunkB, hin);
        scan_pass3<<<gs, 128, 0, stream>>>(yh, yl, cw, hin);

        dim3 g2(EMB / BN, M_TOT / BM);
        gemm_mfma<HID, true, false, FOURH, EMB><<<g2, 256, 0, stream>>>(
            nullptr, yh, yl, w2, out, nullptr, nullptr);
    } else if (ws_size >= sliceBytes) {
        // ---- per-batch sliced path (same byte footprint as the fp32 slice) ----
        unsigned short* yh = (unsigned short*)ws;
        unsigned short* yl = yh + (size_t)SEQ * FOURH;
        float* chunkA = (float*)(ws + 2 * sliceY);
        float* chunkB = chunkA + (size_t)NHEADS * NC * HD;
        float* hin    = chunkB + (size_t)NHEADS * NC * HD;

        for (int b = 0; b < BSZ; ++b) {
            const float* xb = x   + (size_t)b * SEQ * EMB;
            float*       ob = out + (size_t)b * SEQ * EMB;

            dim3 g1(FOURH / BN, SEQ / BM);
            gemm_mfma<EMB, false, true, EMB, FOURH><<<g1, 256, 0, stream>>>(
                xb, nullptr, nullptr, w1, nullptr, yh, yl);

            dim3 gs(NC, NHEADS);
            scan_pass1<<<gs, 128, 0, stream>>>(yh, yl, cw, chunkA, chunkB);
            scan_pass2<<<NHEADS, 128, 0, stream>>>(chunkA, chunkB, hin);
            scan_pass3<<<gs, 128, 0, stream>>>(yh, yl, cw, hin);

            dim3 g2(EMB / BN, SEQ / BM);
            gemm_mfma<HID, true, false, FOURH, EMB><<<g2, 256, 0, stream>>>(
                nullptr, yh, yl, w2, ob, nullptr, nullptr);
        }
    } else {
        fprintf(stderr, "[kernel_launch] ws_size=%zu < sliceBytes=%zu — aborting cleanly\n",
                ws_size, sliceBytes);
        hipMemsetAsync(d_out, 0, (size_t)out_size * sizeof(float), stream);
    }
}

// Round 5
// 2158.354 us; speedup vs baseline: 2.1913x; 1.6373x over previous
//
#include <hip/hip_runtime.h>
#include <cstdint>
#include <cstddef>
#include <cstdio>

// Problem constants (fixed by the reference)
namespace {
constexpr int EMB    = 1024;
constexpr int HID    = 2048;
constexpr int FOURH  = 4 * HID;       // 8192
constexpr int NHEADS = 16;
constexpr int HD     = HID / NHEADS;  // 128
constexpr int BSZ    = 4;
constexpr int SEQ    = 4096;
constexpr int M_TOT  = BSZ * SEQ;     // 16384
constexpr int CH     = 64;            // scan chunk length (was 256: latency-starved)
constexpr int NC     = SEQ / CH;      // 64
constexpr int BH     = BSZ * NHEADS;  // 64

constexpr int BM = 128, BN = 128, BK = 32;
constexpr int LDT = 40;               // LDS row pitch in ushorts (2-way banks only = free)
}

typedef short  bf16x8  __attribute__((ext_vector_type(8)));
typedef float  f32x4   __attribute__((ext_vector_type(4)));
typedef unsigned short usx4 __attribute__((ext_vector_type(4)));
typedef unsigned short usx8 __attribute__((ext_vector_type(8)));

__device__ __forceinline__ unsigned short f2bf(float x) {
    uint32_t u = __float_as_uint(x);
    u += 0x7FFFu + ((u >> 16) & 1u);          // RNE
    return (unsigned short)(u >> 16);
}
__device__ __forceinline__ float bf2f(unsigned short h) {
    return __uint_as_float(((uint32_t)h) << 16);
}
__device__ __forceinline__ void split_store4(const float4 v,
                                             unsigned short* __restrict__ dh,
                                             unsigned short* __restrict__ dl) {
    usx4 h, l;
    h[0] = f2bf(v.x); l[0] = f2bf(v.x - bf2f(h[0]));
    h[1] = f2bf(v.y); l[1] = f2bf(v.y - bf2f(h[1]));
    h[2] = f2bf(v.z); l[2] = f2bf(v.z - bf2f(h[2]));
    h[3] = f2bf(v.w); l[3] = f2bf(v.w - bf2f(h[3]));
    *(usx4*)dh = h;
    *(usx4*)dl = l;
}

// ---------------------------------------------------------------------------
// Split-bf16 MFMA GEMM: C[M,N] = A[M,K] * B[N,K]^T
//   a*b ~= ah*bh + ah*bl + al*bh  (al*bl dropped, ~2^-16 rel)
// ---------------------------------------------------------------------------
template<int K, bool ASPLIT, bool CSPLIT, int LDA, int LDC>
__global__ __launch_bounds__(256, 2)
void gemm_mfma(const float* __restrict__ Af,
               const unsigned short* __restrict__ Ah,
               const unsigned short* __restrict__ Al,
               const float* __restrict__ Bf,
               float* __restrict__ Cf,
               unsigned short* __restrict__ Ch,
               unsigned short* __restrict__ Cl)
{
    __shared__ unsigned short Ash[BM][LDT], Asl[BM][LDT];
    __shared__ unsigned short Bsh[BN][LDT], Bsl[BN][LDT];

    const int tid  = threadIdx.x;
    const int lane = tid & 63;
    const int wv   = tid >> 6;
    const int wr   = (wv >> 1) * 64;
    const int wc   = (wv & 1) * 64;
    const int m0   = blockIdx.y * BM;
    const int n0   = blockIdx.x * BN;

    const int srow = tid >> 1;
    const int skq  = (tid & 1) * 16;

    f32x4 acc[4][4];
#pragma unroll
    for (int i = 0; i < 4; ++i)
#pragma unroll
        for (int j = 0; j < 4; ++j) acc[i][j] = (f32x4){0.f, 0.f, 0.f, 0.f};

    constexpr int NKT = K / BK;

    float4 b0, b1, b2, b3;
    float4 a0, a1, a2, a3;
    usx8 ah0, ah1, al0, al1;

    auto prefetch = [&](int kt) {
        const float* bp = Bf + (size_t)(n0 + srow) * K + kt * BK + skq;
        b0 = *(const float4*)(bp + 0);
        b1 = *(const float4*)(bp + 4);
        b2 = *(const float4*)(bp + 8);
        b3 = *(const float4*)(bp + 12);
        if constexpr (!ASPLIT) {
            const float* ap = Af + (size_t)(m0 + srow) * LDA + kt * BK + skq;
            a0 = *(const float4*)(ap + 0);
            a1 = *(const float4*)(ap + 4);
            a2 = *(const float4*)(ap + 8);
            a3 = *(const float4*)(ap + 12);
        } else {
            const unsigned short* ph = Ah + (size_t)(m0 + srow) * LDA + kt * BK + skq;
            const unsigned short* pl = Al + (size_t)(m0 + srow) * LDA + kt * BK + skq;
            ah0 = *(const usx8*)(ph);
            ah1 = *(const usx8*)(ph + 8);
            al0 = *(const usx8*)(pl);
            al1 = *(const usx8*)(pl + 8);
        }
    };

    prefetch(0);

    for (int kt = 0; kt < NKT; ++kt) {
        __syncthreads();
        split_store4(b0, &Bsh[srow][skq + 0],  &Bsl[srow][skq + 0]);
        split_store4(b1, &Bsh[srow][skq + 4],  &Bsl[srow][skq + 4]);
        split_store4(b2, &Bsh[srow][skq + 8],  &Bsl[srow][skq + 8]);
        split_store4(b3, &Bsh[srow][skq + 12], &Bsl[srow][skq + 12]);
        if constexpr (!ASPLIT) {
            split_store4(a0, &Ash[srow][skq + 0],  &Asl[srow][skq + 0]);
            split_store4(a1, &Ash[srow][skq + 4],  &Asl[srow][skq + 4]);
            split_store4(a2, &Ash[srow][skq + 8],  &Asl[srow][skq + 8]);
            split_store4(a3, &Ash[srow][skq + 12], &Asl[srow][skq + 12]);
        } else {
            *(usx8*)&Ash[srow][skq + 0] = ah0;
            *(usx8*)&Ash[srow][skq + 8] = ah1;
            *(usx8*)&Asl[srow][skq + 0] = al0;
            *(usx8*)&Asl[srow][skq + 8] = al1;
        }
        __syncthreads();

        if (kt + 1 < NKT) prefetch(kt + 1);

        const int fr = lane & 15;
        const int fk = (lane >> 4) * 8;
        bf16x8 fah[4], fal[4], fbh[4], fbl[4];
#pragma unroll
        for (int i = 0; i < 4; ++i) {
            fah[i] = *(const bf16x8*)&Ash[wr + i * 16 + fr][fk];
            fal[i] = *(const bf16x8*)&Asl[wr + i * 16 + fr][fk];
            fbh[i] = *(const bf16x8*)&Bsh[wc + i * 16 + fr][fk];
            fbl[i] = *(const bf16x8*)&Bsl[wc + i * 16 + fr][fk];
        }
#pragma unroll
        for (int i = 0; i < 4; ++i)
#pragma unroll
            for (int j = 0; j < 4; ++j) {
                acc[i][j] = __builtin_amdgcn_mfma_f32_16x16x32_bf16(fah[i], fbh[j], acc[i][j], 0, 0, 0);
                acc[i][j] = __builtin_amdgcn_mfma_f32_16x16x32_bf16(fah[i], fbl[j], acc[i][j], 0, 0, 0);
                acc[i][j] = __builtin_amdgcn_mfma_f32_16x16x32_bf16(fal[i], fbh[j], acc[i][j], 0, 0, 0);
            }
    }

    // epilogue: C/D frag layout col = lane&15, row = (lane>>4)*4 + r  [m89/m91]
    const int fr = lane & 15;
    const int fq = lane >> 4;
#pragma unroll
    for (int i = 0; i < 4; ++i)
#pragma unroll
        for (int j = 0; j < 4; ++j)
#pragma unroll
            for (int r = 0; r < 4; ++r) {
                const int row = m0 + wr + i * 16 + fq * 4 + r;
                const int col = n0 + wc + j * 16 + fr;
                const float v = acc[i][j][r];
                if constexpr (CSPLIT) {
                    const unsigned short h = f2bf(v);
                    Ch[(size_t)row * LDC + col] = h;
                    Cl[(size_t)row * LDC + col] = f2bf(v - bf2f(h));
                } else {
                    Cf[(size_t)row * LDC + col] = v;
                }
            }
}

// ---------------------------------------------------------------------------
// Scan over split-bf16 y. 3-pass chunked; CH=64 so the sliced path launches
// 1024 blocks (4/CU, 8 waves/CU) — latency hiding via TLP, plus unroll-8 MLP.
// ---------------------------------------------------------------------------
__device__ __forceinline__ float sigmoidf_(float x) {
    return 1.f / (1.f + __expf(-x));
}
__device__ __forceinline__ float yld(const unsigned short* __restrict__ yh,
                                     const unsigned short* __restrict__ yl,
                                     size_t idx) {
    return bf2f(yh[idx]) + bf2f(yl[idx]);
}

__global__ __launch_bounds__(128)
void scan_pass1(const unsigned short* __restrict__ yh,
                const unsigned short* __restrict__ yl,
                const float* __restrict__ cw,
                float* __restrict__ chunkA, float* __restrict__ chunkB)
{
    const int d     = threadIdx.x;
    const int chunk = blockIdx.x;
    const int bh    = blockIdx.y;
    const int b = bh >> 4, n = bh & 15;
    const int s0 = chunk * CH;

    const int cf  = 2 * HID + n * (2 * HD) + d;
    const int ci  = cf + HD;
    const int chh = HID + n * HD + d;

    const size_t base = (size_t)b * SEQ * FOURH;
    const float4 wf = *(const float4*)(cw + (size_t)(n * (2 * HD) + d) * 4);
    const float4 wi = *(const float4*)(cw + (size_t)(n * (2 * HD) + HD + d) * 4);

    float f1 = 0.f, f2 = 0.f, f3 = 0.f, i1 = 0.f, i2 = 0.f, i3 = 0.f;
    if (s0 > 0) {
        f1 = yld(yh, yl, base + (size_t)(s0 - 3) * FOURH + cf);
        f2 = yld(yh, yl, base + (size_t)(s0 - 2) * FOURH + cf);
        f3 = yld(yh, yl, base + (size_t)(s0 - 1) * FOURH + cf);
        i1 = yld(yh, yl, base + (size_t)(s0 - 3) * FOURH + ci);
        i2 = yld(yh, yl, base + (size_t)(s0 - 2) * FOURH + ci);
        i3 = yld(yh, yl, base + (size_t)(s0 - 1) * FOURH + ci);
    }

    float A = 1.f, Bv = 0.f;
    size_t rowb = base + (size_t)s0 * FOURH;
#pragma unroll 8
    for (int s = 0; s < CH; ++s, rowb += FOURH) {
        const float f0 = yld(yh, yl, rowb + cf);
        const float i0 = yld(yh, yl, rowb + ci);
        const float hh = yld(yh, yl, rowb + chh);
        const float fc = wf.x * f1 + wf.y * f2 + wf.z * f3 + wf.w * f0;
        const float ic = wi.x * i1 + wi.y * i2 + wi.z * i3 + wi.w * i0;
        f1 = f2; f2 = f3; f3 = f0;
        i1 = i2; i2 = i3; i3 = i0;
        const float fs = sigmoidf_(fc);
        const float is = sigmoidf_(ic);
        const float dn = 1.f / (fs + is + 1e-4f);
        const float a  = fs * dn;
        const float bb = hh * is * dn;
        Bv = a * Bv + bb;
        A *= a;
    }
    const size_t idx = ((size_t)bh * NC + chunk) * HD + d;
    chunkA[idx] = A;
    chunkB[idx] = Bv;
}

__global__ __launch_bounds__(128)
void scan_pass2(const float* __restrict__ chunkA, const float* __restrict__ chunkB,
                float* __restrict__ hin)
{
    const int d  = threadIdx.x;
    const int bh = blockIdx.x;
    float h = 0.f;
    for (int c = 0; c < NC; ++c) {
        const size_t idx = ((size_t)bh * NC + c) * HD + d;
        hin[idx] = h;
        h = chunkA[idx] * h + chunkB[idx];
    }
}

__global__ __launch_bounds__(128)
void scan_pass3(unsigned short* __restrict__ yh,
                unsigned short* __restrict__ yl,
                const float* __restrict__ cw,
                const float* __restrict__ hin)
{
    const int d     = threadIdx.x;
    const int chunk = blockIdx.x;
    const int bh    = blockIdx.y;
    const int b = bh >> 4, n = bh & 15;
    const int s0 = chunk * CH;

    const int cf  = 2 * HID + n * (2 * HD) + d;
    const int ci  = cf + HD;
    const int chh = HID + n * HD + d;
    const int co1 = n * HD + d;

    const size_t base = (size_t)b * SEQ * FOURH;
    const float4 wf = *(const float4*)(cw + (size_t)(n * (2 * HD) + d) * 4);
    const float4 wi = *(const float4*)(cw + (size_t)(n * (2 * HD) + HD + d) * 4);

    float f1 = 0.f, f2 = 0.f, f3 = 0.f, i1 = 0.f, i2 = 0.f, i3 = 0.f;
    if (s0 > 0) {
        f1 = yld(yh, yl, base + (size_t)(s0 - 3) * FOURH + cf);
        f2 = yld(yh, yl, base + (size_t)(s0 - 2) * FOURH + cf);
        f3 = yld(yh, yl, base + (size_t)(s0 - 1) * FOURH + cf);
        i1 = yld(yh, yl, base + (size_t)(s0 - 3) * FOURH + ci);
        i2 = yld(yh, yl, base + (size_t)(s0 - 2) * FOURH + ci);
        i3 = yld(yh, yl, base + (size_t)(s0 - 1) * FOURH + ci);
    }

    float h = hin[((size_t)bh * NC + chunk) * HD + d];

    size_t rowb = base + (size_t)s0 * FOURH;
#pragma unroll 8
    for (int s = 0; s < CH; ++s, rowb += FOURH) {
        const float f0 = yld(yh, yl, rowb + cf);
        const float i0 = yld(yh, yl, rowb + ci);
        const float hv = yld(yh, yl, rowb + chh);
        const float fc = wf.x * f1 + wf.y * f2 + wf.z * f3 + wf.w * f0;
        const float ic = wi.x * i1 + wi.y * i2 + wi.z * i3 + wi.w * i0;
        f1 = f2; f2 = f3; f3 = f0;
        i1 = i2; i2 = i3; i3 = i0;
        const float fs = sigmoidf_(fc);
        const float is = sigmoidf_(ic);
        const float dn = 1.f / (fs + is + 1e-4f);
        const float a  = fs * dn;
        const float bb = hv * is * dn;
        h = a * h + bb;
        const float o1  = yld(yh, yl, rowb + co1);
        const float g   = o1 * sigmoidf_(o1) * h;  // silu(out1) * h
        const unsigned short gh = f2bf(g);
        yh[rowb + co1] = gh;
        yl[rowb + co1] = f2bf(g - bf2f(gh));
    }
}

// ---------------------------------------------------------------------------
extern "C" void kernel_launch(void* const* d_in, const int* in_sizes, int n_in,
                              void* d_out, int out_size, void* d_ws, size_t ws_size,
                              hipStream_t stream)
{
    (void)in_sizes; (void)n_in;
    const float* x  = (const float*)d_in[0];   // [B,S,E]
    const float* w1 = (const float*)d_in[1];   // [4H,E]
    const float* w2 = (const float*)d_in[2];   // [E,H]
    const float* cw = (const float*)d_in[3];   // [2H,4]
    float* out = (float*)d_out;                // [B,S,E]

    const size_t sideFloats = (size_t)3 * BH * NC * HD;                    // ~6 MB
    const size_t fullY   = (size_t)M_TOT * FOURH * sizeof(unsigned short); // 256 MiB / plane
    const size_t sliceY  = (size_t)SEQ * FOURH * sizeof(unsigned short);   // 64 MiB / plane
    const size_t fullBytes  = 2 * fullY  + sideFloats * sizeof(float);
    const size_t sliceBytes = 2 * sliceY + sideFloats * sizeof(float);

    char* ws = (char*)d_ws;

    if (ws_size >= fullBytes) {
        // ---- full-M path ----
        unsigned short* yh = (unsigned short*)ws;
        unsigned short* yl = yh + (size_t)M_TOT * FOURH;
        float* chunkA = (float*)(ws + 2 * fullY);
        float* chunkB = chunkA + (size_t)BH * NC * HD;
        float* hin    = chunkB + (size_t)BH * NC * HD;

        dim3 g1(FOURH / BN, M_TOT / BM);
        gemm_mfma<EMB, false, true, EMB, FOURH><<<g1, 256, 0, stream>>>(
            x, nullptr, nullptr, w1, nullptr, yh, yl);

        dim3 gs(NC, BH);
        scan_pass1<<<gs, 128, 0, stream>>>(yh, yl, cw, chunkA, chunkB);
        scan_pass2<<<BH, 128, 0, stream>>>(chunkA, chunkB, hin);
        scan_pass3<<<gs, 128, 0, stream>>>(yh, yl, cw, hin);

        dim3 g2(EMB / BN, M_TOT / BM);
        gemm_mfma<HID, true, false, FOURH, EMB><<<g2, 256, 0, stream>>>(
            nullptr, yh, yl, w2, out, nullptr, nullptr);
    } else if (ws_size >= sliceBytes) {
        // ---- per-batch sliced path ----
        unsigned short* yh = (unsigned short*)ws;
        unsigned short* yl = yh + (size_t)SEQ * FOURH;
        float* chunkA = (float*)(ws + 2 * sliceY);
        float* chunkB = chunkA + (size_t)NHEADS * NC * HD;
        float* hin    = chunkB + (size_t)NHEADS * NC * HD;

        for (int b = 0; b < BSZ; ++b) {
            const float* xb = x   + (size_t)b * SEQ * EMB;
            float*       ob = out + (size_t)b * SEQ * EMB;

            dim3 g1(FOURH / BN, SEQ / BM);
            gemm_mfma<EMB, false, true, EMB, FOURH><<<g1, 256, 0, stream>>>(
                xb, nullptr, nullptr, w1, nullptr, yh, yl);

            dim3 gs(NC, NHEADS);
            scan_pass1<<<gs, 128, 0, stream>>>(yh, yl, cw, chunkA, chunkB);
            scan_pass2<<<NHEADS, 128, 0, stream>>>(chunkA, chunkB, hin);
            scan_pass3<<<gs, 128, 0, stream>>>(yh, yl, cw, hin);

            dim3 g2(EMB / BN, SEQ / BM);
            gemm_mfma<HID, true, false, FOURH, EMB><<<g2, 256, 0, stream>>>(
                nullptr, yh, yl, w2, ob, nullptr, nullptr);
        }
    } else {
        fprintf(stderr, "[kernel_launch] ws_size=%zu < sliceBytes=%zu — aborting cleanly\n",
                ws_size, sliceBytes);
        hipMemsetAsync(d_out, 0, (size_t)out_size * sizeof(float), stream);
    }
}